// Round 5
// baseline (108.261 us; speedup 1.0000x reference)
//
#include <hip/hip_runtime.h>
#include <math.h>

#define HW 16384   // 128*128
#define NB 4       // batch

typedef unsigned short u16;
typedef _Float16 f16;
typedef _Float16 f16x8 __attribute__((ext_vector_type(8)));
typedef float f32x4 __attribute__((ext_vector_type(4)));

__device__ __forceinline__ int imin(int a, int b) { return a < b ? a : b; }
__device__ __forceinline__ int imax(int a, int b) { return a > b ? a : b; }
__device__ __forceinline__ u16 f2h(float f) {
  _Float16 h = (_Float16)f;
  return __builtin_bit_cast(u16, h);
}

// ---------------- transpose x (B,C,HW) f32 -> xTh (B,HW,C) f16 ----------------
__global__ __launch_bounds__(256) void k_transpose(const float* __restrict__ x,
                                                   u16* __restrict__ xTh) {
  __shared__ float t[64][65];
  const int b = blockIdx.y;
  const int hw0 = blockIdx.x << 6;
  const int tid = threadIdx.x, lane = tid & 63, grp = tid >> 6;
#pragma unroll
  for (int r = 0; r < 16; ++r) {
    const int c = (grp << 4) + r;
    t[c][lane] = x[((b << 6) + c) * HW + hw0 + lane];
  }
  __syncthreads();
#pragma unroll
  for (int r = 0; r < 16; ++r) {
    const int hwl = (grp << 4) + r;
    xTh[(b * HW + hw0 + hwl) * 64 + lane] = f2h(t[lane][hwl]);
  }
}

// ---------------- pack weights to f16, plain K(=c)-contiguous per tap --------
// wPk [k 9][o 64][c 64] ; woPk [k 9][o 32 (27 live, rest zero)][c 64]
__global__ __launch_bounds__(256) void k_pack(const float* __restrict__ weight,
                                              const float* __restrict__ w_off,
                                              u16* __restrict__ wPk,
                                              u16* __restrict__ woPk) {
  const int g = blockIdx.x * 256 + threadIdx.x;
  if (g < 36864) {
    const int k = g >> 12, rem = g & 4095, o = rem >> 6, c = rem & 63;
    wPk[g] = f2h(weight[((o << 6) + c) * 9 + k]);
  }
  if (g < 18432) {
    const int k = g >> 11, rem = g & 2047, o = rem >> 6, c = rem & 63;
    woPk[g] = (o < 27) ? f2h(w_off[((o << 6) + c) * 9 + k]) : (u16)0;
  }
}

// ---------------- offset conv via MFMA, barrier-free direct fragments --------
// wave = 16 px, all 32 o (27 live). Lane: n = lane&15 (pixel), ks = lane>>4 (k-slice).
__global__ __launch_bounds__(256, 4) void k_offconv(const u16* __restrict__ xTh,
                                                    const u16* __restrict__ woPk,
                                                    const float* __restrict__ b_off,
                                                    float* __restrict__ offmT) {
  const int tid = threadIdx.x, lane = tid & 63, wv = tid >> 6;
  const int b = blockIdx.y;
  const int px0 = (blockIdx.x << 6) + (wv << 4);
  const int n = lane & 15, ks = lane >> 4;
  const int pxm = px0 + n, h = pxm >> 7, w = pxm & 127;
  const u16* xb = xTh + ((b * HW) << 6);

  f32x4 acc[2];
#pragma unroll
  for (int i = 0; i < 2; ++i) acc[i] = (f32x4)0.f;

#pragma unroll 1
  for (int k = 0; k < 9; ++k) {
    const int y = h + k / 3 - 1, xx = w + k % 3 - 1;
    f16x8 bf0 = (f16x8)(f16)0.f, bf1 = (f16x8)(f16)0.f;
    if (y >= 0 && y < 128 && xx >= 0 && xx < 128) {
      const u16* bp = xb + ((((y << 7) + xx)) << 6) + (ks << 3);
      bf0 = *(const f16x8*)bp;
      bf1 = *(const f16x8*)(bp + 32);
    }
    const u16* wkp = woPk + (k << 11) + (n << 6) + (ks << 3);
#pragma unroll
    for (int i = 0; i < 2; ++i) {
      const f16x8 a0 = *(const f16x8*)(wkp + (i << 10));
      const f16x8 a1 = *(const f16x8*)(wkp + (i << 10) + 32);
      acc[i] = __builtin_amdgcn_mfma_f32_16x16x32_f16(a0, bf0, acc[i], 0, 0, 0);
      acc[i] = __builtin_amdgcn_mfma_f32_16x16x32_f16(a1, bf1, acc[i], 0, 0, 0);
    }
  }

  // epilogue: direct transposed-plane stores (16 consecutive px per 16-lane grp)
#pragma unroll
  for (int i = 0; i < 2; ++i)
#pragma unroll
    for (int r = 0; r < 4; ++r) {
      const int oc = i * 16 + (ks << 2) + r;
      if (oc < 27) {
        float sv = acc[i][r] + b_off[oc];
        if (oc >= 18) sv = 1.f / (1.f + expf(-sv));
        offmT[(b * 28 + oc) * HW + pxm] = sv;
      }
    }
}

// ---------------- deformable gather + MFMA, barrier-free direct fragments ----
// wave = 16 px, all 64 o. Lane gathers its own B-fragment (4 corners x 16B,
// pk_fma blend in f16 registers); A-fragments direct from L1-resident wPk.
__global__ __launch_bounds__(256, 4) void k_deform(const u16* __restrict__ xTh,
                                                   const float* __restrict__ offmT,
                                                   const u16* __restrict__ wPk,
                                                   const float* __restrict__ bias,
                                                   float* __restrict__ out) {
  const int tid = threadIdx.x, lane = tid & 63, wv = tid >> 6;
  const int b = blockIdx.y;
  const int px0 = (blockIdx.x << 6) + (wv << 4);
  const int n = lane & 15, ks = lane >> 4;
  const int pxm = px0 + n, h = pxm >> 7, w = pxm & 127;
  const float* omb = offmT + b * 28 * HW + pxm;
  const u16* xb = xTh + ((b * HW) << 6);

  f32x4 acc[4];
#pragma unroll
  for (int i = 0; i < 4; ++i) acc[i] = (f32x4)0.f;

  // offm prefetch (1 tap ahead)
  float d0 = omb[0], d1 = omb[HW], d2 = omb[18 * HW];

#pragma unroll 1
  for (int k = 0; k < 9; ++k) {
    // ---- meta for tap k
    const float py = (float)(h + k / 3 - 1) + d0;
    const float pxx = (float)(w + k % 3 - 1) + d1;
    const float m = d2;
    if (k < 8) {  // prefetch next tap's offsets under this tap's work
      d0 = omb[(2 * k + 2) * HW];
      d1 = omb[(2 * k + 3) * HW];
      d2 = omb[(19 + k) * HW];
    }
    const float fy = floorf(py), fx = floorf(pxx);
    const int y0 = (int)fy, x0 = (int)fx;
    const int y1 = y0 + 1, x1 = x0 + 1;
    const float ly = py - fy, lx = pxx - fx;
    const bool vy0 = (y0 >= 0) && (y0 < 128), vy1 = (y1 >= 0) && (y1 < 128);
    const bool vx0 = (x0 >= 0) && (x0 < 128), vx1 = (x1 >= 0) && (x1 < 128);
    const int y0c = imin(imax(y0, 0), 127), y1c = imin(imax(y1, 0), 127);
    const int x0c = imin(imax(x0, 0), 127), x1c = imin(imax(x1, 0), 127);
    float wt[4];
    int ci[4];
    wt[0] = (vy0 && vx0) ? (1.f - ly) * (1.f - lx) * m : 0.f;
    wt[1] = (vy0 && vx1) ? (1.f - ly) * lx * m : 0.f;
    wt[2] = (vy1 && vx0) ? ly * (1.f - lx) * m : 0.f;
    wt[3] = (vy1 && vx1) ? ly * lx * m : 0.f;
    ci[0] = (((y0c << 7) + x0c) << 6) + (ks << 3);
    ci[1] = (((y0c << 7) + x1c) << 6) + (ks << 3);
    ci[2] = (((y1c << 7) + x0c) << 6) + (ks << 3);
    ci[3] = (((y1c << 7) + x1c) << 6) + (ks << 3);

    // ---- corner loads (both K=32 halves), then pk_fma blend
    f16x8 cA[4], cB[4];
#pragma unroll
    for (int q = 0; q < 4; ++q) {
      cA[q] = *(const f16x8*)(xb + ci[q]);
      cB[q] = *(const f16x8*)(xb + ci[q] + 32);
    }
    f16x8 bf0 = (f16x8)(f16)0.f, bf1 = (f16x8)(f16)0.f;
#pragma unroll
    for (int q = 0; q < 4; ++q) {
      const f16x8 w8 = (f16x8)(f16)wt[q];
      bf0 = __builtin_elementwise_fma(cA[q], w8, bf0);
      bf1 = __builtin_elementwise_fma(cB[q], w8, bf1);
    }

    // ---- MFMA over 4 o-tiles x 2 K-halves (A from L1-resident wPk)
    const u16* wkp = wPk + (k << 12) + (n << 6) + (ks << 3);
#pragma unroll
    for (int i = 0; i < 4; ++i) {
      const f16x8 a0 = *(const f16x8*)(wkp + (i << 10));
      const f16x8 a1 = *(const f16x8*)(wkp + (i << 10) + 32);
      acc[i] = __builtin_amdgcn_mfma_f32_16x16x32_f16(a0, bf0, acc[i], 0, 0, 0);
      acc[i] = __builtin_amdgcn_mfma_f32_16x16x32_f16(a1, bf1, acc[i], 0, 0, 0);
    }
  }

  // epilogue: direct stores (16 consecutive px per 16-lane group)
#pragma unroll
  for (int i = 0; i < 4; ++i)
#pragma unroll
    for (int r = 0; r < 4; ++r) {
      const int o = i * 16 + (ks << 2) + r;
      out[(b * 64 + o) * HW + pxm] = acc[i][r] + bias[o];
    }
}

extern "C" void kernel_launch(void* const* d_in, const int* in_sizes, int n_in,
                              void* d_out, int out_size, void* d_ws, size_t ws_size,
                              hipStream_t stream) {
  (void)in_sizes; (void)n_in; (void)out_size; (void)ws_size;
  const float* x      = (const float*)d_in[0];
  const float* w_off  = (const float*)d_in[1];
  const float* b_off  = (const float*)d_in[2];
  const float* weight = (const float*)d_in[3];
  const float* bias   = (const float*)d_in[4];
  float* out = (float*)d_out;

  char* wsb = (char*)d_ws;
  u16* xTh     = (u16*)wsb;                       // 8,388,608 B
  float* offmT = (float*)(wsb + 8388608);         // 7,340,032 B
  u16* wPk     = (u16*)(wsb + 15728640);          // 73,728 B
  u16* woPk    = (u16*)(wsb + 15802368);          // 36,864 B

  k_transpose<<<dim3(256, NB), 256, 0, stream>>>(x, xTh);
  k_pack<<<dim3(144), 256, 0, stream>>>(weight, w_off, wPk, woPk);
  k_offconv<<<dim3(256, NB), 256, 0, stream>>>(xTh, woPk, b_off, offmT);
  k_deform<<<dim3(256, NB), 256, 0, stream>>>(xTh, offmT, wPk, bias, out);
}

// Round 6
// 62.497 us; speedup vs baseline: 1.7323x; 1.7323x over previous
//
#include <hip/hip_runtime.h>
#include <math.h>

#define HW 16384   // 128*128
#define NB 4       // batch

typedef unsigned short u16;
typedef _Float16 f16;
typedef _Float16 f16x8 __attribute__((ext_vector_type(8)));
typedef float f32x4 __attribute__((ext_vector_type(4)));

__device__ __forceinline__ int imin(int a, int b) { return a < b ? a : b; }
__device__ __forceinline__ int imax(int a, int b) { return a > b ? a : b; }
__device__ __forceinline__ u16 f2h(float f) {
  _Float16 h = (_Float16)f;
  return __builtin_bit_cast(u16, h);
}
// async global->LDS, 16B/lane; lds ptr must be wave-uniform (lane*16 implicit)
__device__ __forceinline__ void gld16(const u16* g, u16* l) {
  __builtin_amdgcn_global_load_lds((const __attribute__((address_space(1))) void*)g,
                                   (__attribute__((address_space(3))) void*)l, 16, 0, 0);
}

// ---------------- transpose x (B,C,HW) f32 -> xTh (B,HW,C) f16 ----------------
__global__ __launch_bounds__(256) void k_transpose(const float* __restrict__ x,
                                                   u16* __restrict__ xTh) {
  __shared__ float t[64][65];
  const int b = blockIdx.y;
  const int hw0 = blockIdx.x << 6;
  const int tid = threadIdx.x, lane = tid & 63, grp = tid >> 6;
#pragma unroll
  for (int r = 0; r < 16; ++r) {
    const int c = (grp << 4) + r;
    t[c][lane] = x[((b << 6) + c) * HW + hw0 + lane];
  }
  __syncthreads();
#pragma unroll
  for (int r = 0; r < 16; ++r) {
    const int hwl = (grp << 4) + r;
    xTh[(b * HW + hw0 + hwl) * 64 + lane] = f2h(t[lane][hwl]);
  }
}

// ---------------- pack weights to f16, pre-swizzled (c ^ ((o&7)<<3)) ----------
// wSwz [k 9][o 64][c'64] ; woSwz [k 9][o 32 (27 live, rest 0)][c'64]
__global__ __launch_bounds__(256) void k_pack(const float* __restrict__ weight,
                                              const float* __restrict__ w_off,
                                              u16* __restrict__ wSwz,
                                              u16* __restrict__ woSwz) {
  const int g = blockIdx.x * 256 + threadIdx.x;
  if (g < 36864) {
    const int k = g >> 12, rem = g & 4095, o = rem >> 6, c = rem & 63;
    wSwz[(k << 12) + (o << 6) + (c ^ ((o & 7) << 3))] = f2h(weight[((o << 6) + c) * 9 + k]);
  }
  if (g < 18432) {
    const int k = g >> 11, rem = g & 2047, o = rem >> 6, c = rem & 63;
    woSwz[(k << 11) + (o << 6) + (c ^ ((o & 7) << 3))] =
        (o < 27) ? f2h(w_off[((o << 6) + c) * 9 + k]) : (u16)0;
  }
}

// ---------------- offset conv: LDS weights (once), barrier-free loop ----------
// 512 thr = 8 waves x 16 px; wave: 16 px x 32 o (27 live)
__global__ __launch_bounds__(512, 4) void k_offconv(const u16* __restrict__ xTh,
                                                    const u16* __restrict__ woSwz,
                                                    const float* __restrict__ b_off,
                                                    float* __restrict__ offmT) {
  __shared__ u16 wl[9 * 32 * 64];  // 36864 B
  const int tid = threadIdx.x, lane = tid & 63, wv = tid >> 6;
  const int b = blockIdx.y;
  const int px0 = (blockIdx.x << 7) + (wv << 4);
  const int n = lane & 15, ks = lane >> 4;
  const int pxm = px0 + n, h = pxm >> 7, w = pxm & 127;
  const u16* xb = xTh + ((b * HW) << 6);

  // stage all 9 taps once (2304 chunks of 16B)
#pragma unroll
  for (int it = 0; it < 4; ++it) {
    const int u = it * 512 + (wv << 6);
    gld16(woSwz + ((u + lane) << 3), wl + (u << 3));
  }
  if (wv < 4) {
    const int u = 2048 + (wv << 6);
    gld16(woSwz + ((u + lane) << 3), wl + (u << 3));
  }
  __syncthreads();

  const int slot0 = ((ks << 4) ^ ((n & 7) << 4));
  const int rowb = n * 128 + slot0;

  f32x4 acc[2];
#pragma unroll
  for (int i = 0; i < 2; ++i) acc[i] = (f32x4)0.f;

#pragma unroll 1
  for (int k = 0; k < 9; ++k) {
    const int y = h + k / 3 - 1, xx = w + k % 3 - 1;
    const bool v = (y >= 0) && (y < 128) && (xx >= 0) && (xx < 128);
    const int yc = imin(imax(y, 0), 127), xc = imin(imax(xx, 0), 127);
    const u16* bp = xb + ((((yc << 7) + xc)) << 6) + (ks << 3);
    f16x8 b0 = *(const f16x8*)bp;
    f16x8 b1 = *(const f16x8*)(bp + 32);
    if (!v) { b0 = (f16x8)(f16)0.f; b1 = (f16x8)(f16)0.f; }
    const char* wb = (const char*)wl + (k << 12) + rowb;
#pragma unroll
    for (int i = 0; i < 2; ++i) {
      const f16x8 a0 = *(const f16x8*)(wb + (i << 11));
      const f16x8 a1 = *(const f16x8*)(wb + ((i << 11) ^ 0) + ((slot0 ^ 64) - slot0));
      acc[i] = __builtin_amdgcn_mfma_f32_16x16x32_f16(a0, b0, acc[i], 0, 0, 0);
      acc[i] = __builtin_amdgcn_mfma_f32_16x16x32_f16(a1, b1, acc[i], 0, 0, 0);
    }
  }

  // epilogue: transposed-plane stores
#pragma unroll
  for (int i = 0; i < 2; ++i)
#pragma unroll
    for (int r = 0; r < 4; ++r) {
      const int oc = i * 16 + (ks << 2) + r;
      if (oc < 27) {
        float sv = acc[i][r] + b_off[oc];
        if (oc >= 18) sv = 1.f / (1.f + expf(-sv));
        offmT[(b * 28 + oc) * HW + pxm] = sv;
      }
    }
}

// ---------------- deformable gather + MFMA: LDS weights, 2-phase pipeline ----
// 512 thr = 8 waves x 16 px; wave: 16 px x 64 o (4 o-tiles)
__global__ __launch_bounds__(512, 4) void k_deform(const u16* __restrict__ xTh,
                                                   const float* __restrict__ offmT,
                                                   const u16* __restrict__ wSwz,
                                                   const float* __restrict__ bias,
                                                   float* __restrict__ out) {
  __shared__ u16 wl[9 * 64 * 64];  // 73728 B
  const int tid = threadIdx.x, lane = tid & 63, wv = tid >> 6;
  const int b = blockIdx.y;
  const int px0 = (blockIdx.x << 7) + (wv << 4);
  const int n = lane & 15, ks = lane >> 4;
  const int pxm = px0 + n, h = pxm >> 7, w = pxm & 127;
  const float* omb = offmT + b * 28 * HW + pxm;
  const u16* xb = xTh + ((b * HW) << 6);

  // stage all 9 taps of weights once (4608 chunks of 16B)
#pragma unroll
  for (int it = 0; it < 9; ++it) {
    const int u = it * 512 + (wv << 6);
    gld16(wSwz + ((u + lane) << 3), wl + (u << 3));
  }
  __syncthreads();

  const int slot0 = ((ks << 4) ^ ((n & 7) << 4));
  const int rowb = n * 128 + slot0;
  const int flip = (slot0 ^ 64) - slot0;  // +/-64: half-1 slot offset

  f32x4 acc[4];
#pragma unroll
  for (int i = 0; i < 4; ++i) acc[i] = (f32x4)0.f;

  auto meta = [&](int k, float* wt, int* ci) {
    const float d0 = omb[(2 * k) * HW];
    const float d1 = omb[(2 * k + 1) * HW];
    const float d2 = omb[(18 + k) * HW];
    const float py = (float)(h + k / 3 - 1) + d0;
    const float pxx = (float)(w + k % 3 - 1) + d1;
    const float fy = floorf(py), fx = floorf(pxx);
    const int y0 = (int)fy, x0 = (int)fx;
    const int y1 = y0 + 1, x1 = x0 + 1;
    const float ly = py - fy, lx = pxx - fx;
    const bool vy0 = (y0 >= 0) && (y0 < 128), vy1 = (y1 >= 0) && (y1 < 128);
    const bool vx0 = (x0 >= 0) && (x0 < 128), vx1 = (x1 >= 0) && (x1 < 128);
    const int y0c = imin(imax(y0, 0), 127), y1c = imin(imax(y1, 0), 127);
    const int x0c = imin(imax(x0, 0), 127), x1c = imin(imax(x1, 0), 127);
    wt[0] = (vy0 && vx0) ? (1.f - ly) * (1.f - lx) * d2 : 0.f;
    wt[1] = (vy0 && vx1) ? (1.f - ly) * lx * d2 : 0.f;
    wt[2] = (vy1 && vx0) ? ly * (1.f - lx) * d2 : 0.f;
    wt[3] = (vy1 && vx1) ? ly * lx * d2 : 0.f;
    ci[0] = (((y0c << 7) + x0c) << 6) + (ks << 3);
    ci[1] = (((y0c << 7) + x1c) << 6) + (ks << 3);
    ci[2] = (((y1c << 7) + x0c) << 6) + (ks << 3);
    ci[3] = (((y1c << 7) + x1c) << 6) + (ks << 3);
  };
  auto gather = [&](const int* ci, f16x8* g) {
#pragma unroll
    for (int q = 0; q < 4; ++q) {
      g[2 * q] = *(const f16x8*)(xb + ci[q]);
      g[2 * q + 1] = *(const f16x8*)(xb + ci[q] + 32);
    }
  };
  auto blend_mfma = [&](const float* wt, const f16x8* g, int k) {
    f16x8 b0 = (f16x8)(f16)0.f, b1 = (f16x8)(f16)0.f;
#pragma unroll
    for (int q = 0; q < 4; ++q) {
      const f16x8 w8 = (f16x8)(f16)wt[q];
      b0 = __builtin_elementwise_fma(g[2 * q], w8, b0);
      b1 = __builtin_elementwise_fma(g[2 * q + 1], w8, b1);
    }
    const char* wb = (const char*)wl + (k << 13) + rowb;
#pragma unroll
    for (int i = 0; i < 4; ++i) {
      const f16x8 a0 = *(const f16x8*)(wb + (i << 11));
      const f16x8 a1 = *(const f16x8*)(wb + (i << 11) + flip);
      acc[i] = __builtin_amdgcn_mfma_f32_16x16x32_f16(a0, b0, acc[i], 0, 0, 0);
      acc[i] = __builtin_amdgcn_mfma_f32_16x16x32_f16(a1, b1, acc[i], 0, 0, 0);
    }
  };

  float wtA[4], wtB[4];
  int ciA[4], ciB[4];
  f16x8 gA[8], gB[8];

  meta(0, wtA, ciA);
  gather(ciA, gA);
#pragma unroll 1
  for (int kp = 0; kp < 4; ++kp) {
    meta(2 * kp + 1, wtB, ciB);
    gather(ciB, gB);
    blend_mfma(wtA, gA, 2 * kp);
    meta(2 * kp + 2, wtA, ciA);
    gather(ciA, gA);
    blend_mfma(wtB, gB, 2 * kp + 1);
  }
  blend_mfma(wtA, gA, 8);

  // epilogue: direct stores (16 consecutive px per 16-lane group)
#pragma unroll
  for (int i = 0; i < 4; ++i)
#pragma unroll
    for (int r = 0; r < 4; ++r) {
      const int o = i * 16 + (ks << 2) + r;
      out[(b * 64 + o) * HW + pxm] = acc[i][r] + bias[o];
    }
}

extern "C" void kernel_launch(void* const* d_in, const int* in_sizes, int n_in,
                              void* d_out, int out_size, void* d_ws, size_t ws_size,
                              hipStream_t stream) {
  (void)in_sizes; (void)n_in; (void)out_size; (void)ws_size;
  const float* x      = (const float*)d_in[0];
  const float* w_off  = (const float*)d_in[1];
  const float* b_off  = (const float*)d_in[2];
  const float* weight = (const float*)d_in[3];
  const float* bias   = (const float*)d_in[4];
  float* out = (float*)d_out;

  char* wsb = (char*)d_ws;
  u16* xTh     = (u16*)wsb;                       // 8,388,608 B
  float* offmT = (float*)(wsb + 8388608);         // 7,340,032 B
  u16* wSwz    = (u16*)(wsb + 15728640);          // 73,728 B
  u16* woSwz   = (u16*)(wsb + 15802368);          // 36,864 B

  k_transpose<<<dim3(256, NB), 256, 0, stream>>>(x, xTh);
  k_pack<<<dim3(144), 256, 0, stream>>>(weight, w_off, wSwz, woSwz);
  k_offconv<<<dim3(128, NB), 512, 0, stream>>>(xTh, woSwz, b_off, offmT);
  k_deform<<<dim3(128, NB), 512, 0, stream>>>(xTh, offmT, wSwz, bias, out);
}

// Round 7
// 56.545 us; speedup vs baseline: 1.9146x; 1.1053x over previous
//
#include <hip/hip_runtime.h>
#include <math.h>

#define HW 16384   // 128*128
#define NB 4       // batch

typedef unsigned short u16;
typedef _Float16 f16;
typedef _Float16 f16x8 __attribute__((ext_vector_type(8)));
typedef float f32x4 __attribute__((ext_vector_type(4)));

__device__ __forceinline__ int imin(int a, int b) { return a < b ? a : b; }
__device__ __forceinline__ int imax(int a, int b) { return a > b ? a : b; }
__device__ __forceinline__ u16 f2h(float f) {
  _Float16 h = (_Float16)f;
  return __builtin_bit_cast(u16, h);
}
// async global->LDS, 16B/lane; lds ptr must be wave-uniform (lane*16 implicit)
__device__ __forceinline__ void gld16(const u16* g, u16* l) {
  __builtin_amdgcn_global_load_lds((const __attribute__((address_space(1))) void*)g,
                                   (__attribute__((address_space(3))) void*)l, 16, 0, 0);
}

// ---------- prep: transpose x -> xTh (f16 channel-last) + pack/swizzle weights ----
// blocks x<256: transpose tile for batch y. blocks x>=256 (y==0): weight pack.
__global__ __launch_bounds__(256) void k_prep(const float* __restrict__ x,
                                              const float* __restrict__ weight,
                                              const float* __restrict__ w_off,
                                              u16* __restrict__ xTh,
                                              u16* __restrict__ wSwz,
                                              u16* __restrict__ woSwz) {
  const int bx = blockIdx.x, b = blockIdx.y, tid = threadIdx.x;
  if (bx >= 256) {
    if (b != 0) return;
    const int g = (bx - 256) * 256 + tid;
    if (g < 36864) {
      const int k = g >> 12, rem = g & 4095, o = rem >> 6, c = rem & 63;
      wSwz[(k << 12) + (o << 6) + (c ^ ((o & 7) << 3))] =
          f2h(weight[((o << 6) + c) * 9 + k]);
    }
    if (g < 18432) {
      const int k = g >> 11, rem = g & 2047, o = rem >> 6, c = rem & 63;
      woSwz[(k << 11) + (o << 6) + (c ^ ((o & 7) << 3))] =
          (o < 27) ? f2h(w_off[((o << 6) + c) * 9 + k]) : (u16)0;
    }
    return;
  }
  __shared__ float t[64][65];
  const int hw0 = bx << 6;
  const int lane = tid & 63, grp = tid >> 6;
#pragma unroll
  for (int r = 0; r < 16; ++r) {
    const int c = (grp << 4) + r;
    t[c][lane] = x[((b << 6) + c) * HW + hw0 + lane];
  }
  __syncthreads();
#pragma unroll
  for (int it = 0; it < 4; ++it) {
    const int e = (it << 8) + tid, hwl = e >> 4, cq = e & 15;
    const unsigned lo = (unsigned)f2h(t[(cq << 2) + 0][hwl]) |
                        ((unsigned)f2h(t[(cq << 2) + 1][hwl]) << 16);
    const unsigned hi = (unsigned)f2h(t[(cq << 2) + 2][hwl]) |
                        ((unsigned)f2h(t[(cq << 2) + 3][hwl]) << 16);
    *(uint2*)&xTh[((b * HW + hw0 + hwl) << 6) + (cq << 2)] = make_uint2(lo, hi);
  }
}

// ---------- fused offset-conv + deformable conv ----------
// 1024 thr = 16 waves x 16 px = 256 px/block; grid (64, NB) = 1 block/CU.
// LDS: wo 36864 + wl 73728 + moff 32896 = 143488 B.
__global__ __launch_bounds__(1024, 4) void k_main(const u16* __restrict__ xTh,
                                                  const u16* __restrict__ wSwz,
                                                  const u16* __restrict__ woSwz,
                                                  const float* __restrict__ b_off,
                                                  const float* __restrict__ bias,
                                                  float* __restrict__ out) {
  __shared__ u16 wo[9 * 32 * 64];
  __shared__ u16 wl[9 * 64 * 64];
  __shared__ float moff[32 * 257];
  const int tid = threadIdx.x, lane = tid & 63, wv = tid >> 6;
  const int b = blockIdx.y;
  const int pxb = blockIdx.x << 8;
  const int n = lane & 15, ks = lane >> 4;
  const int pxl = (wv << 4) + n;
  const int pxm = pxb + pxl;
  const int h = pxm >> 7, w = pxm & 127;
  const u16* xb = xTh + ((b * HW) << 6);

  // ---- stage both weight arrays once (108 wave-calls of 1KB)
  for (int u = wv; u < 108; u += 16) {
    if (u < 36)
      gld16(woSwz + (((u << 6) + lane) << 3), wo + (u << 9));
    else {
      const int v = u - 36;
      gld16(wSwz + (((v << 6) + lane) << 3), wl + (v << 9));
    }
  }
  __syncthreads();

  const int slot0 = (ks << 4) ^ ((n & 7) << 4);
  const int rowb = n * 128 + slot0;
  const int flip = (slot0 ^ 64) - slot0;  // second K-half slot offset

  // ================= phase 1: offset conv (16 px x 32 o per wave) ===========
  {
    f32x4 acc[2];
#pragma unroll
    for (int i = 0; i < 2; ++i) acc[i] = (f32x4)0.f;
#pragma unroll 1
    for (int k = 0; k < 9; ++k) {
      const int y = h + k / 3 - 1, xx = w + k % 3 - 1;
      const bool v = (y >= 0) && (y < 128) && (xx >= 0) && (xx < 128);
      const int yc = imin(imax(y, 0), 127), xc = imin(imax(xx, 0), 127);
      const u16* bp = xb + (((yc << 7) + xc) << 6) + (ks << 3);
      f16x8 b0 = *(const f16x8*)bp;
      f16x8 b1 = *(const f16x8*)(bp + 32);
      if (!v) { b0 = (f16x8)(f16)0.f; b1 = (f16x8)(f16)0.f; }
      const char* wb = (const char*)wo + (k << 12) + rowb;
#pragma unroll
      for (int i = 0; i < 2; ++i) {
        const f16x8 a0 = *(const f16x8*)(wb + (i << 11));
        const f16x8 a1 = *(const f16x8*)(wb + (i << 11) + flip);
        acc[i] = __builtin_amdgcn_mfma_f32_16x16x32_f16(a0, b0, acc[i], 0, 0, 0);
        acc[i] = __builtin_amdgcn_mfma_f32_16x16x32_f16(a1, b1, acc[i], 0, 0, 0);
      }
    }
#pragma unroll
    for (int i = 0; i < 2; ++i)
#pragma unroll
      for (int r = 0; r < 4; ++r) {
        const int oc = i * 16 + (ks << 2) + r;
        if (oc < 27) {
          float sv = acc[i][r] + b_off[oc];
          if (oc >= 18) sv = 1.f / (1.f + expf(-sv));
          moff[oc * 257 + pxl] = sv;
        }
      }
  }
  __syncthreads();

  // ================= phase 2: deformable gather + contraction ===============
  f32x4 acc[4];
#pragma unroll
  for (int i = 0; i < 4; ++i) acc[i] = (f32x4)0.f;

  auto meta = [&](int k, float* wt, int* ci) {
    const float d0 = moff[(2 * k) * 257 + pxl];
    const float d1 = moff[(2 * k + 1) * 257 + pxl];
    const float d2 = moff[(18 + k) * 257 + pxl];
    const float py = (float)(h + k / 3 - 1) + d0;
    const float pxx = (float)(w + k % 3 - 1) + d1;
    const float fy = floorf(py), fx = floorf(pxx);
    const int y0 = (int)fy, x0 = (int)fx;
    const int y1 = y0 + 1, x1 = x0 + 1;
    const float ly = py - fy, lx = pxx - fx;
    const bool vy0 = (y0 >= 0) && (y0 < 128), vy1 = (y1 >= 0) && (y1 < 128);
    const bool vx0 = (x0 >= 0) && (x0 < 128), vx1 = (x1 >= 0) && (x1 < 128);
    const int y0c = imin(imax(y0, 0), 127), y1c = imin(imax(y1, 0), 127);
    const int x0c = imin(imax(x0, 0), 127), x1c = imin(imax(x1, 0), 127);
    wt[0] = (vy0 && vx0) ? (1.f - ly) * (1.f - lx) * d2 : 0.f;
    wt[1] = (vy0 && vx1) ? (1.f - ly) * lx * d2 : 0.f;
    wt[2] = (vy1 && vx0) ? ly * (1.f - lx) * d2 : 0.f;
    wt[3] = (vy1 && vx1) ? ly * lx * d2 : 0.f;
    ci[0] = (((y0c << 7) + x0c) << 6) + (ks << 3);
    ci[1] = (((y0c << 7) + x1c) << 6) + (ks << 3);
    ci[2] = (((y1c << 7) + x0c) << 6) + (ks << 3);
    ci[3] = (((y1c << 7) + x1c) << 6) + (ks << 3);
  };
  auto gather = [&](const int* ci, f16x8* g) {
#pragma unroll
    for (int q = 0; q < 4; ++q) {
      g[2 * q] = *(const f16x8*)(xb + ci[q]);
      g[2 * q + 1] = *(const f16x8*)(xb + ci[q] + 32);
    }
  };
  auto blend_mfma = [&](const float* wt, const f16x8* g, int k) {
    f16x8 b0 = (f16x8)(f16)0.f, b1 = (f16x8)(f16)0.f;
#pragma unroll
    for (int q = 0; q < 4; ++q) {
      const f16x8 w8 = (f16x8)(f16)wt[q];
      b0 = __builtin_elementwise_fma(g[2 * q], w8, b0);
      b1 = __builtin_elementwise_fma(g[2 * q + 1], w8, b1);
    }
    const char* wb = (const char*)wl + (k << 13) + rowb;
#pragma unroll
    for (int i = 0; i < 4; ++i) {
      const f16x8 a0 = *(const f16x8*)(wb + (i << 11));
      const f16x8 a1 = *(const f16x8*)(wb + (i << 11) + flip);
      acc[i] = __builtin_amdgcn_mfma_f32_16x16x32_f16(a0, b0, acc[i], 0, 0, 0);
      acc[i] = __builtin_amdgcn_mfma_f32_16x16x32_f16(a1, b1, acc[i], 0, 0, 0);
    }
  };

  float wtA[4], wtB[4];
  int ciA[4], ciB[4];
  f16x8 gA[8], gB[8];

  meta(0, wtA, ciA);
  gather(ciA, gA);
#pragma unroll 1
  for (int kp = 0; kp < 4; ++kp) {
    meta(2 * kp + 1, wtB, ciB);
    gather(ciB, gB);
    blend_mfma(wtA, gA, 2 * kp);
    meta(2 * kp + 2, wtA, ciA);
    gather(ciA, gA);
    blend_mfma(wtB, gB, 2 * kp + 1);
  }
  blend_mfma(wtA, gA, 8);

  // epilogue: direct stores (16 consecutive px per 16-lane group)
#pragma unroll
  for (int i = 0; i < 4; ++i)
#pragma unroll
    for (int r = 0; r < 4; ++r) {
      const int o = i * 16 + (ks << 2) + r;
      out[(b * 64 + o) * HW + pxm] = acc[i][r] + bias[o];
    }
}

extern "C" void kernel_launch(void* const* d_in, const int* in_sizes, int n_in,
                              void* d_out, int out_size, void* d_ws, size_t ws_size,
                              hipStream_t stream) {
  (void)in_sizes; (void)n_in; (void)out_size; (void)ws_size;
  const float* x      = (const float*)d_in[0];
  const float* w_off  = (const float*)d_in[1];
  const float* b_off  = (const float*)d_in[2];
  const float* weight = (const float*)d_in[3];
  const float* bias   = (const float*)d_in[4];
  float* out = (float*)d_out;

  char* wsb = (char*)d_ws;
  u16* xTh   = (u16*)wsb;                 // 8,388,608 B
  u16* wSwz  = (u16*)(wsb + 8388608);     // 73,728 B
  u16* woSwz = (u16*)(wsb + 8462336);     // 36,864 B

  k_prep<<<dim3(400, NB), 256, 0, stream>>>(x, weight, w_off, xTh, wSwz, woSwz);
  k_main<<<dim3(64, NB), 1024, 0, stream>>>(xTh, wSwz, woSwz, b_off, bias, out);
}

// Round 8
// 31.216 us; speedup vs baseline: 3.4681x; 1.8114x over previous
//
#include <hip/hip_runtime.h>
#include <math.h>

#define HW 16384   // 128*128
#define NB 4       // batch

typedef unsigned short u16;
typedef _Float16 f16;
typedef _Float16 f16x8 __attribute__((ext_vector_type(8)));
typedef float f32x4 __attribute__((ext_vector_type(4)));

__device__ __forceinline__ u16 f2h(float f) {
  _Float16 h = (_Float16)f;
  return __builtin_bit_cast(u16, h);
}
__device__ __forceinline__ float h2f(u16 u) {
  return (float)__builtin_bit_cast(_Float16, u);
}
// async global->LDS, 16B/lane; lds base wave-uniform (lane*16 implicit), src per-lane
__device__ __forceinline__ void gld16(const u16* g, u16* l) {
  __builtin_amdgcn_global_load_lds((const __attribute__((address_space(1))) void*)g,
                                   (__attribute__((address_space(3))) void*)l, 16, 0, 0);
}

// ---------- prep: transpose x -> xTh (f16 channel-last) + pack fragment weights ----
// wlF [k][i 4][s 2][lane 64][e 8]  (o = i*16+(l&15), c = s*32+(l>>4)*8+e)
// woF [k][i2 2][s 2][lane 64][e 8] (o = i2*16+(l&15), zero for o>=27)
__global__ __launch_bounds__(256) void k_prep(const float* __restrict__ x,
                                              const float* __restrict__ weight,
                                              const float* __restrict__ w_off,
                                              u16* __restrict__ xTh,
                                              u16* __restrict__ wlF,
                                              u16* __restrict__ woF,
                                              u16* __restrict__ zp) {
  const int bx = blockIdx.x, b = blockIdx.y, tid = threadIdx.x;
  if (bx >= 256) {
    if (b != 0) return;
    const int g = (bx - 256) * 256 + tid;
    if (g < 36864) {
      const int e = g & 7, l = (g >> 3) & 63, rem = g >> 9;
      const int s = rem & 1, i = (rem >> 1) & 3, k = rem >> 3;
      const int o = (i << 4) + (l & 15);
      const int c = (s << 5) + ((l >> 4) << 3) + e;
      wlF[g] = f2h(weight[(o * 64 + c) * 9 + k]);
    }
    if (g < 18432) {
      const int e = g & 7, l = (g >> 3) & 63, rem = g >> 9;
      const int s = rem & 1, i2 = (rem >> 1) & 1, k = rem >> 2;
      const int o = (i2 << 4) + (l & 15);
      const int c = (s << 5) + ((l >> 4) << 3) + e;
      woF[g] = (o < 27) ? f2h(w_off[(o * 64 + c) * 9 + k]) : (u16)0;
    }
    if (g < 64) zp[g] = 0;
    return;
  }
  __shared__ float t[64][65];
  const int hw0 = bx << 6;
  const int lane = tid & 63, grp = tid >> 6;
#pragma unroll
  for (int r = 0; r < 16; ++r) {
    const int c = (grp << 4) + r;
    t[c][lane] = x[((b << 6) + c) * HW + hw0 + lane];
  }
  __syncthreads();
#pragma unroll
  for (int it = 0; it < 4; ++it) {
    const int e = (it << 8) + tid, hwl = e >> 4, cq = e & 15;
    const unsigned lo = (unsigned)f2h(t[(cq << 2) + 0][hwl]) |
                        ((unsigned)f2h(t[(cq << 2) + 1][hwl]) << 16);
    const unsigned hi = (unsigned)f2h(t[(cq << 2) + 2][hwl]) |
                        ((unsigned)f2h(t[(cq << 2) + 3][hwl]) << 16);
    *(uint2*)&xTh[((b * HW + hw0 + hwl) << 6) + (cq << 2)] = make_uint2(lo, hi);
  }
}

// ---------- fused deformable conv, halo-in-LDS ----------
// 512 thr = 8 waves; block = 16x16 px tile; wave: 32 px (2 rows) x 64 o.
// LDS: halo 24x24x128B (73728) + s_w 73728 (wo then wl) + dyx 9216 + m16 4608 = 161280 B
__global__ __launch_bounds__(512, 2) void k_main(const u16* __restrict__ xTh,
                                                 const u16* __restrict__ wlF,
                                                 const u16* __restrict__ woF,
                                                 const u16* __restrict__ zp,
                                                 const float* __restrict__ b_off,
                                                 const float* __restrict__ bias,
                                                 float* __restrict__ out) {
  __shared__ __align__(16) u16 s_halo[24 * 24 * 64];
  __shared__ __align__(16) u16 s_w[9 * 8 * 512];
  __shared__ __align__(4) unsigned s_dyx[9 * 256];
  __shared__ __align__(4) u16 s_m[9 * 256];

  const int tid = threadIdx.x, lane = tid & 63, wv = tid >> 6;
  const int b = blockIdx.y, bx = blockIdx.x;
  const int h0 = (bx >> 3) << 4, w0 = (bx & 7) << 4;
  const int n = lane & 15, ks = lane >> 4;
  const u16* xb = xTh + ((b * HW) << 6);

  // ---- stage halo (24 rows x 3 KB, swizzled source) + wo fragments
#pragma unroll
  for (int rr = 0; rr < 3; ++rr) {
    const int cy = wv + (rr << 3);
    const int yg = h0 - 4 + cy;
    const bool rowok = (unsigned)yg < 128u;
#pragma unroll
    for (int g3 = 0; g3 < 3; ++g3) {
      const int cell = cy * 24 + (g3 << 3) + (lane >> 3);
      const int xg = w0 - 4 + (g3 << 3) + (lane >> 3);
      const int u = (lane & 7) ^ (cell & 7);
      const u16* src = (rowok && (unsigned)xg < 128u)
                           ? xb + (((yg << 7) + xg) << 6) + (u << 3)
                           : zp + ((lane & 7) << 3);
      gld16(src, s_halo + ((cy * 24 + (g3 << 3)) << 6));
    }
  }
  for (int u = wv; u < 36; u += 8)
    gld16(woF + (u << 9) + (lane << 3), s_w + (u << 9));
  __syncthreads();

  // ================= phase 1: offset conv =================
  {
    f32x4 accO[2][2];
#pragma unroll
    for (int i = 0; i < 2; ++i)
#pragma unroll
      for (int j = 0; j < 2; ++j) accO[i][j] = (f32x4)0.f;

#pragma unroll
    for (int k = 0; k < 9; ++k) {
      const int ki = k / 3 - 1, kj = k % 3 - 1;
      f16x8 bh[2][2];
#pragma unroll
      for (int j = 0; j < 2; ++j) {
        const int cell = ((wv << 1) + j + ki + 4) * 24 + (n + kj + 4);
#pragma unroll
        for (int s = 0; s < 2; ++s)
          bh[j][s] = *(const f16x8*)(s_halo + (cell << 6) +
                                     ((((s << 2) + ks) ^ (cell & 7)) << 3));
      }
#pragma unroll
      for (int i2 = 0; i2 < 2; ++i2)
#pragma unroll
        for (int s = 0; s < 2; ++s) {
          const f16x8 aw =
              *(const f16x8*)(s_w + (((((k << 1) + i2) << 1) + s) << 9) + (lane << 3));
#pragma unroll
          for (int j = 0; j < 2; ++j)
            accO[i2][j] = __builtin_amdgcn_mfma_f32_16x16x32_f16(aw, bh[j][s],
                                                                 accO[i2][j], 0, 0, 0);
        }
    }
    // epilogue -> packed f16 offsets/masks in LDS
#pragma unroll
    for (int i2 = 0; i2 < 2; ++i2)
#pragma unroll
      for (int r = 0; r < 4; ++r) {
        const int oc = (i2 << 4) + (ks << 2) + r;
        if (oc < 27) {
          const float bo = b_off[oc];
#pragma unroll
          for (int j = 0; j < 2; ++j) {
            const int px = (wv << 5) + (j << 4) + n;
            float v = accO[i2][j][r] + bo;
            if (oc >= 18) {
              v = 1.f / (1.f + expf(-v));
              s_m[((oc - 18) << 8) + px] = f2h(v);
            } else {
              ((u16*)s_dyx)[((((oc >> 1) << 8) + px) << 1) | (oc & 1)] = f2h(v);
            }
          }
        }
      }
  }
  __syncthreads();

  // ---- restage: wl fragments over wo region
  for (int u = wv; u < 72; u += 8)
    gld16(wlF + (u << 9) + (lane << 3), s_w + (u << 9));
  __syncthreads();

  // ================= phase 2: deformable gather + contraction =================
  f32x4 acc[4][2];
#pragma unroll
  for (int i = 0; i < 4; ++i)
#pragma unroll
    for (int j = 0; j < 2; ++j) acc[i][j] = (f32x4)0.f;

  const float xbase = (float)(w0 + n);

#pragma unroll 1
  for (int k = 0; k < 9; ++k) {
    const int ki = k / 3 - 1, kj = k % 3 - 1;
    f16 wth[2][4];
    int c00[2], y0g[2], x0g[2];
    bool ok = true;
#pragma unroll
    for (int j = 0; j < 2; ++j) {
      const int px = (wv << 5) + (j << 4) + n;
      const unsigned dd = s_dyx[(k << 8) + px];
      const float dy = h2f((u16)(dd & 0xffff));
      const float dx = h2f((u16)(dd >> 16));
      const float m = h2f(s_m[(k << 8) + px]);
      const float py = (float)(h0 + (wv << 1) + j + ki) + dy;
      const float pxx = xbase + (float)kj + dx;
      const float fy = floorf(py), fx = floorf(pxx);
      const float ly = py - fy, lx = pxx - fx;
      const int y0 = (int)fy, x0 = (int)fx;
      const int cy = y0 - h0 + 4, cx = x0 - w0 + 4;
      ok = ok && ((unsigned)cy <= 22u) && ((unsigned)cx <= 22u);
      wth[j][0] = (f16)((1.f - ly) * (1.f - lx) * m);
      wth[j][1] = (f16)((1.f - ly) * lx * m);
      wth[j][2] = (f16)(ly * (1.f - lx) * m);
      wth[j][3] = (f16)(ly * lx * m);
      c00[j] = cy * 24 + cx;
      y0g[j] = y0; x0g[j] = x0;
    }

    f16x8 bf[2][2];
    if (__all(ok)) {
#pragma unroll
      for (int j = 0; j < 2; ++j) {
        const int cq[4] = {c00[j], c00[j] + 1, c00[j] + 24, c00[j] + 25};
#pragma unroll
        for (int s = 0; s < 2; ++s) {
          f16x8 a = (f16x8)(f16)0.f;
#pragma unroll
          for (int q = 0; q < 4; ++q) {
            const int c = cq[q];
            const f16x8 v = *(const f16x8*)(s_halo + (c << 6) +
                                            ((((s << 2) + ks) ^ (c & 7)) << 3));
            a = __builtin_elementwise_fma(v, (f16x8)wth[j][q], a);
          }
          bf[j][s] = a;
        }
      }
    } else {
      // rare fallback: global gather with zero-page padding
#pragma unroll
      for (int j = 0; j < 2; ++j) {
        bf[j][0] = (f16x8)(f16)0.f;
        bf[j][1] = (f16x8)(f16)0.f;
#pragma unroll
        for (int q = 0; q < 4; ++q) {
          const int yq = y0g[j] + (q >> 1), xq = x0g[j] + (q & 1);
          const u16* src = ((unsigned)yq < 128u && (unsigned)xq < 128u)
                               ? xb + (((yq << 7) + xq) << 6)
                               : zp;
#pragma unroll
          for (int s = 0; s < 2; ++s) {
            const f16x8 v = *(const f16x8*)(src + (s << 5) + (ks << 3));
            bf[j][s] = __builtin_elementwise_fma(v, (f16x8)wth[j][q], bf[j][s]);
          }
        }
      }
    }

#pragma unroll
    for (int i = 0; i < 4; ++i)
#pragma unroll
      for (int s = 0; s < 2; ++s) {
        const f16x8 af =
            *(const f16x8*)(s_w + (((((k << 2) + i) << 1) + s) << 9) + (lane << 3));
#pragma unroll
        for (int j = 0; j < 2; ++j)
          acc[i][j] = __builtin_amdgcn_mfma_f32_16x16x32_f16(af, bf[j][s],
                                                             acc[i][j], 0, 0, 0);
      }
  }

  // epilogue: direct stores (16 px = 64B contiguous per 16-lane group)
#pragma unroll
  for (int i = 0; i < 4; ++i) {
    const float4 bv = *(const float4*)(bias + (i << 4) + (ks << 2));
    const float bvr[4] = {bv.x, bv.y, bv.z, bv.w};
#pragma unroll
    for (int r = 0; r < 4; ++r) {
      const int o = (i << 4) + (ks << 2) + r;
#pragma unroll
      for (int j = 0; j < 2; ++j) {
        const int y = h0 + (wv << 1) + j;
        out[((b << 6) + o) * HW + (y << 7) + w0 + n] = acc[i][j][r] + bvr[r];
      }
    }
  }
}

extern "C" void kernel_launch(void* const* d_in, const int* in_sizes, int n_in,
                              void* d_out, int out_size, void* d_ws, size_t ws_size,
                              hipStream_t stream) {
  (void)in_sizes; (void)n_in; (void)out_size; (void)ws_size;
  const float* x      = (const float*)d_in[0];
  const float* w_off  = (const float*)d_in[1];
  const float* b_off  = (const float*)d_in[2];
  const float* weight = (const float*)d_in[3];
  const float* bias   = (const float*)d_in[4];
  float* out = (float*)d_out;

  char* wsb = (char*)d_ws;
  u16* xTh = (u16*)wsb;                     // 8,388,608 B
  u16* wlF = (u16*)(wsb + 8388608);         // 73,728 B
  u16* woF = (u16*)(wsb + 8462336);         // 36,864 B
  u16* zp  = (u16*)(wsb + 8499200);         // 128 B

  k_prep<<<dim3(400, NB), 256, 0, stream>>>(x, weight, w_off, xTh, wlF, woF, zp);
  k_main<<<dim3(64, NB), 512, 0, stream>>>(xTh, wlF, woF, zp, b_off, bias, out);
}